// Round 15
// baseline (116.556 us; speedup 1.0000x reference)
//
#include <hip/hip_runtime.h>

#define DM   1024
#define SEQ  2048
#define NH   16
#define HD   64
#define ROWS 4096   // B*S = 2*2048

typedef unsigned short u16;
typedef unsigned int   u32;
typedef __attribute__((ext_vector_type(8))) __bf16 bf16x8;
typedef __attribute__((ext_vector_type(4))) float  f32x4;
typedef __attribute__((ext_vector_type(16))) float f32x16;

__device__ __forceinline__ u16 f2bf(float f) {
  u32 u = __builtin_bit_cast(u32, f);
  u += 0x7fffu + ((u >> 16) & 1u);   // RNE (finite values only)
  return (u16)(u >> 16);
}

__device__ __forceinline__ void async16(const void* g, void* lds) {
  __builtin_amdgcn_global_load_lds((const __attribute__((address_space(1))) u32*)g,
                                   (__attribute__((address_space(3))) u32*)lds, 16, 0, 0);
}

// ---------------- converters ----------------

__global__ __launch_bounds__(256) void k_cvt_act(const float* __restrict__ q,
                                                 const float* __restrict__ k,
                                                 const float* __restrict__ v,
                                                 u16* __restrict__ dst) {
  const float* src = blockIdx.z == 0 ? q : (blockIdx.z == 1 ? k : v);
  u16* d = dst + (size_t)blockIdx.z * ((size_t)ROWS * DM);
  size_t i = ((size_t)blockIdx.x * 256 + threadIdx.x) * 8;
  float4 a = *(const float4*)(src + i);
  float4 b = *(const float4*)(src + i + 4);
  u32 w0 = (u32)f2bf(a.x) | ((u32)f2bf(a.y) << 16);
  u32 w1 = (u32)f2bf(a.z) | ((u32)f2bf(a.w) << 16);
  u32 w2 = (u32)f2bf(b.x) | ((u32)f2bf(b.y) << 16);
  u32 w3 = (u32)f2bf(b.z) | ((u32)f2bf(b.w) << 16);
  uint4 o4; o4.x = w0; o4.y = w1; o4.z = w2; o4.w = w3;
  *(uint4*)(d + i) = o4;
}

// Wt[n][k] = W[k][n], bf16
__global__ __launch_bounds__(256) void k_cvt_wt(const float* __restrict__ Wq,
                                                const float* __restrict__ Wk,
                                                const float* __restrict__ Wv,
                                                u16* __restrict__ wt) {
  __shared__ float t[32][33];
  const float* W = blockIdx.z == 0 ? Wq : (blockIdx.z == 1 ? Wk : Wv);
  u16* D = wt + (size_t)blockIdx.z * (DM * DM);
  int bx = blockIdx.x * 32, by = blockIdx.y * 32;
  int x = threadIdx.x, y = threadIdx.y;
  for (int i = 0; i < 32; i += 8) t[y + i][x] = W[(size_t)(by + y + i) * DM + bx + x];
  __syncthreads();
  for (int i = 0; i < 32; i += 8) D[(size_t)(bx + y + i) * DM + by + x] = f2bf(t[x][y + i]);
}

// ---------------- GEMM: C = A * Wt^T (bf16), BK=32 (round-6 proven version). ---------
// Q-proj gets 0.125*log2(e) folded in. XCD-aware block swizzle (T1).

__global__ __launch_bounds__(256) void k_gemm(const u16* __restrict__ Abase,
                                              const u16* __restrict__ Btbase,
                                              u16* __restrict__ Cbase) {
  __shared__ u16 As[128 * 32];
  __shared__ u16 Bs[128 * 32];
  const int z = blockIdx.z;
  const u16* A  = Abase  + (size_t)z * ((size_t)ROWS * DM);
  const u16* Bt = Btbase + (size_t)z * (DM * DM);
  u16* C        = Cbase  + (size_t)z * ((size_t)ROWS * DM);
  const float sc = (z == 0) ? 0.18033688011112043f : 1.0f;  // 1/8 * log2(e)
  int tid = threadIdx.x, w = tid >> 6, l = tid & 63;
  int fr = l & 15, fq = l >> 4;
  int bid = blockIdx.y * 8 + blockIdx.x;          // 256 per z (256 % 8 == 0)
  int nb  = (bid & 7) * 32 + (bid >> 3);          // XCD chunk remap (bijective)
  int m0 = (nb >> 3) * 128, n0 = (nb & 7) * 128;
  int wr = (w >> 1) * 64, wc = (w & 1) * 64;
  f32x4 acc[4][4];
  for (int i = 0; i < 4; ++i) for (int j = 0; j < 4; ++j) acc[i][j] = (f32x4){0.f, 0.f, 0.f, 0.f};

  for (int k0 = 0; k0 < DM; k0 += 32) {
    __syncthreads();
    for (int c = 0; c < 2; ++c) {
      int loff = (c * 4 + w) * 1024;
      int eoff = (loff >> 1) + l * 8;
      int row = eoff >> 5;
      int blk = (eoff & 31) >> 3;
      int gblk = blk ^ ((row >> 1) & 3);
      async16(A  + (size_t)(m0 + row) * DM + k0 + (gblk << 3), (char*)As + loff);
      async16(Bt + (size_t)(n0 + row) * DM + k0 + (gblk << 3), (char*)Bs + loff);
    }
    __syncthreads();
    bf16x8 af[4], bf[4];
    for (int i = 0; i < 4; ++i) {
      int row = wr + i * 16 + fr;
      af[i] = *(const bf16x8*)(As + row * 32 + ((fq ^ ((row >> 1) & 3)) << 3));
    }
    for (int j = 0; j < 4; ++j) {
      int row = wc + j * 16 + fr;
      bf[j] = *(const bf16x8*)(Bs + row * 32 + ((fq ^ ((row >> 1) & 3)) << 3));
    }
    for (int i = 0; i < 4; ++i)
      for (int j = 0; j < 4; ++j)
        acc[i][j] = __builtin_amdgcn_mfma_f32_16x16x32_bf16(af[i], bf[j], acc[i][j], 0, 0, 0);
  }
  for (int i = 0; i < 4; ++i)
    for (int j = 0; j < 4; ++j)
      for (int jj = 0; jj < 4; ++jj) {
        int row = m0 + wr + i * 16 + fq * 4 + jj;
        int col = n0 + wc + j * 16 + fr;
        C[(size_t)row * DM + col] = f2bf(acc[i][j][jj] * sc);
      }
}

// ---------------- V transpose: Vt[hb][d][s], PV-fragment-ready layout ----------------

__global__ __launch_bounds__(256) void k_vt(const u16* __restrict__ vproj,
                                            u16* __restrict__ vt) {
  __shared__ u16 t[64][64];
  int y = blockIdx.y;            // hb = h*2 + b
  int h = y >> 1, b = y & 1;
  int s0 = blockIdx.x * 64;
  int tid = threadIdx.x;
  for (int c = 0; c < 2; ++c) {
    int rr = c * 32 + (tid >> 3);
    int blk = tid & 7;
    uint4 vv = *(const uint4*)(vproj + (size_t)(b * SEQ + s0 + rr) * DM + h * 64 + blk * 8);
    *(uint4*)(&t[rr][((blk ^ (rr & 7)) * 8)]) = vv;
  }
  __syncthreads();
  for (int c = 0; c < 2; ++c) {
    int d = c * 32 + (tid >> 3);
    int p = tid & 7;                    // phys block
    int B = p ^ (d & 7);
    int g = B >> 1, half = B & 1;
    u16 tmp[8];
    for (int j = 0; j < 8; ++j) {
      int kj = (j < 4) ? (4 * half + j) : (8 + 4 * half + (j - 4));
      int ss = 16 * g + kj;             // logical local key
      tmp[j] = t[ss][((d >> 3) ^ (ss & 7)) * 8 + (d & 7)];
    }
    *(uint4*)(vt + (size_t)(y * 64 + d) * SEQ + s0 + p * 8) = *(uint4*)tmp;
  }
}

// ---------------- attention ----------------
// grid 1024 (XCD-remapped); block = 64 q-rows, KVBLK=128 (16 phases: halves the
// fixed per-phase sync/latency overhead r8-r12 measured as dominant).
// Wave w: qg=w>>1 (32 q-rows), kh=w&1 (64-key chunk of the 128-key tile).
// K tile = 2x8KB [64key][64d] chunks (source-swizzled); V tile = 2x8KB k_vt chunks.
// Swapped QK^T, no max-subtraction, T15 (PV delayed one tile).
// ROUND-8 SYNC SKELETON (proven on HW): plain __syncthreads per phase, guarded
// prefetch, no inline-asm waits. LDS: K dbuf 32KB + V tbuf 48KB = 80KB -> 2/CU.

__global__ __launch_bounds__(256, 2) void k_attn(const u16* __restrict__ Qp,
                                                 const u16* __restrict__ Kp,
                                                 const u16* __restrict__ Vt,
                                                 float* __restrict__ att) {
  __shared__ u16 lds[40960];   // 80KB: K dbuf [0,32K), V tbuf [32K,80K)
  const int tid = threadIdx.x, w = tid >> 6, l = tid & 63;
  const int lrow = l & 31, h = l >> 5;
  const int kh = w & 1, qg = w >> 1;
  const int g = blockIdx.x;
  const int vy = (g & 7) * 4 + ((g >> 3) & 3);   // same-vy blocks share an XCD
  const int vx = g >> 5;
  const int head = vy >> 1, b = vy & 1;
  const int hcol = head * 64;
  const int q0w = vx * 64 + qg * 32;

  // Q fragments (B-operand): col=q=lrow, k-elem j -> d = 16*i + 8h + j
  const u16* qrow = Qp + (size_t)(b * SEQ + q0w + lrow) * DM + hcol + h * 8;
  bf16x8 qb0 = *(const bf16x8*)(qrow);
  bf16x8 qb1 = *(const bf16x8*)(qrow + 16);
  bf16x8 qb2 = *(const bf16x8*)(qrow + 32);
  bf16x8 qb3 = *(const bf16x8*)(qrow + 48);

  // fragment byte offsets within a chunk (chunk = kh*8192 within a 16KB buf)
  const int sw = lrow & 7;
  const int fb = kh * 8192 + lrow * 128;
  const int F0 = fb + (((0 + h) ^ sw) << 4);
  const int F1 = fb + (((2 + h) ^ sw) << 4);
  const int F2 = fb + (((4 + h) ^ sw) << 4);
  const int F3 = fb + (((6 + h) ^ sw) << 4);

  // staging: 4 K-issues + 4 V-issues per wave per phase (16KB K + 16KB V per tile)
  u32 koff[4], voff[4];
#pragma unroll
  for (int i = 0; i < 4; ++i) {
    int loff = (w * 4 + i) * 1024;
    int e = (loff >> 1) + l * 8;
    int krow = e >> 6;                              // 0..127 (key within tile)
    int gblk = ((e & 63) >> 3) ^ (krow & 7);        // inverse swizzle on source
    koff[i] = (u32)((b * SEQ + krow) * DM + hcol + gblk * 8);
    int ch = e >> 12;                               // V chunk (0/1)
    int d  = (e >> 6) & 63;
    voff[i] = (u32)((vy * 64 + d) * SEQ + ch * 64 + (e & 63));
  }

  const f32x16 kzero = {};
  f32x16 ot0 = {}, ot1 = {};
  float lacc = 0.f;
  bf16x8 pb00 = {}, pb01 = {}, pb10 = {}, pb11 = {};   // P of tile t-1

  char* base = (char*)lds;
  // prologue: stage tile 0 (K buf0, V buf0)
#pragma unroll
  for (int i = 0; i < 4; ++i) {
    async16(Kp + koff[i], base + (w * 4 + i) * 1024);
    async16(Vt + voff[i], base + 32768 + (w * 4 + i) * 1024);
  }
  __syncthreads();

  int vwr = 1, vcr = 0, vrd = 2;   // V buf indices for tiles t+1, t, t-1
  for (int t = 0; t < SEQ / 128; ++t) {
    // 1) prefetch tile t+1 (guarded; wave-uniform branch)
    if (t + 1 < SEQ / 128) {
      u32 kadv = (u32)(t + 1) * (u32)(128 * DM);
      u32 vadv = (u32)(t + 1) * 128u;
      char* kd = base + ((t + 1) & 1) * 16384;
      char* vd = base + 32768 + vwr * 16384;
#pragma unroll
      for (int i = 0; i < 4; ++i) {
        async16(Kp + kadv + koff[i], kd + (w * 4 + i) * 1024);
        async16(Vt + vadv + voff[i], vd + (w * 4 + i) * 1024);
      }
    }

    // 2) QK^T for tile t (this wave's 64-key chunk; keys 0-31 -> st0, 32-63 -> st1)
    const char* Kb = base + (t & 1) * 16384;
    bf16x8 a0 = *(const bf16x8*)(Kb + F0);
    bf16x8 a1 = *(const bf16x8*)(Kb + F1);
    bf16x8 a2 = *(const bf16x8*)(Kb + F2);
    bf16x8 a3 = *(const bf16x8*)(Kb + F3);
    bf16x8 a4 = *(const bf16x8*)(Kb + 4096 + F0);
    bf16x8 a5 = *(const bf16x8*)(Kb + 4096 + F1);
    bf16x8 a6 = *(const bf16x8*)(Kb + 4096 + F2);
    bf16x8 a7 = *(const bf16x8*)(Kb + 4096 + F3);
    __builtin_amdgcn_s_setprio(1);
    f32x16 st0 = __builtin_amdgcn_mfma_f32_32x32x16_bf16(a0, qb0, kzero, 0, 0, 0);
    f32x16 st1 = __builtin_amdgcn_mfma_f32_32x32x16_bf16(a4, qb0, kzero, 0, 0, 0);
    st0 = __builtin_amdgcn_mfma_f32_32x32x16_bf16(a1, qb1, st0, 0, 0, 0);
    st1 = __builtin_amdgcn_mfma_f32_32x32x16_bf16(a5, qb1, st1, 0, 0, 0);
    st0 = __builtin_amdgcn_mfma_f32_32x32x16_bf16(a2, qb2, st0, 0, 0, 0);
    st1 = __builtin_amdgcn_mfma_f32_32x32x16_bf16(a6, qb2, st1, 0, 0, 0);
    st0 = __builtin_amdgcn_mfma_f32_32x32x16_bf16(a3, qb3, st0, 0, 0, 0);
    st1 = __builtin_amdgcn_mfma_f32_32x32x16_bf16(a7, qb3, st1, 0, 0, 0);
    __builtin_amdgcn_s_setprio(0);

    // 3) PV for tile t-1 (independent -> overlaps QK in the MFMA pipe)
    if (t) {
      const char* Vb = base + 32768 + vrd * 16384;
      bf16x8 vf0 = *(const bf16x8*)(Vb + F0);
      bf16x8 vf1 = *(const bf16x8*)(Vb + F1);
      bf16x8 vf2 = *(const bf16x8*)(Vb + F2);
      bf16x8 vf3 = *(const bf16x8*)(Vb + F3);
      bf16x8 vf4 = *(const bf16x8*)(Vb + 4096 + F0);
      bf16x8 vf5 = *(const bf16x8*)(Vb + 4096 + F1);
      bf16x8 vf6 = *(const bf16x8*)(Vb + 4096 + F2);
      bf16x8 vf7 = *(const bf16x8*)(Vb + 4096 + F3);
      __builtin_amdgcn_s_setprio(1);
      ot0 = __builtin_amdgcn_mfma_f32_32x32x16_bf16(vf0, pb00, ot0, 0, 0, 0);
      ot1 = __builtin_amdgcn_mfma_f32_32x32x16_bf16(vf4, pb00, ot1, 0, 0, 0);
      ot0 = __builtin_amdgcn_mfma_f32_32x32x16_bf16(vf1, pb01, ot0, 0, 0, 0);
      ot1 = __builtin_amdgcn_mfma_f32_32x32x16_bf16(vf5, pb01, ot1, 0, 0, 0);
      ot0 = __builtin_amdgcn_mfma_f32_32x32x16_bf16(vf2, pb10, ot0, 0, 0, 0);
      ot1 = __builtin_amdgcn_mfma_f32_32x32x16_bf16(vf6, pb10, ot1, 0, 0, 0);
      ot0 = __builtin_amdgcn_mfma_f32_32x32x16_bf16(vf3, pb11, ot0, 0, 0, 0);
      ot1 = __builtin_amdgcn_mfma_f32_32x32x16_bf16(vf7, pb11, ot1, 0, 0, 0);
      __builtin_amdgcn_s_setprio(0);
    }

    // 4) softmax numerators for tile t (no max subtraction; scores ~N(0,1))
    {
      f32x16 p;
#pragma unroll
      for (int i = 0; i < 16; ++i) p[i] = __builtin_amdgcn_exp2f(st0[i]);
      float s0 = (p[0] + p[1]) + (p[2] + p[3]);
      float s1 = (p[4] + p[5]) + (p[6] + p[7]);
      float s2 = (p[8] + p[9]) + (p[10] + p[11]);
      float s3 = (p[12] + p[13]) + (p[14] + p[15]);
      lacc += (s0 + s1) + (s2 + s3);
#pragma unroll
      for (int j = 0; j < 8; ++j) { pb00[j] = (__bf16)p[j]; pb01[j] = (__bf16)p[8 + j]; }
    }
    {
      f32x16 p;
#pragma unroll
      for (int i = 0; i < 16; ++i) p[i] = __builtin_amdgcn_exp2f(st1[i]);
      float s0 = (p[0] + p[1]) + (p[2] + p[3]);
      float s1 = (p[4] + p[5]) + (p[6] + p[7]);
      float s2 = (p[8] + p[9]) + (p[10] + p[11]);
      float s3 = (p[12] + p[13]) + (p[14] + p[15]);
      lacc += (s0 + s1) + (s2 + s3);
#pragma unroll
      for (int j = 0; j < 8; ++j) { pb10[j] = (__bf16)p[j]; pb11[j] = (__bf16)p[8 + j]; }
    }

    // 5) end-of-phase barrier (drains this phase's prefetch; frees buffers)
    __syncthreads();

    int tmp = vrd; vrd = vcr; vcr = vwr; vwr = tmp;
  }

  // post-loop: PV for the last tile (V in vrd after final rotation; its buffer
  // was staged at t=NT-2 and drained by that phase's __syncthreads)
  {
    const char* Vb = base + 32768 + vrd * 16384;
    bf16x8 vf0 = *(const bf16x8*)(Vb + F0);
    bf16x8 vf1 = *(const bf16x8*)(Vb + F1);
    bf16x8 vf2 = *(const bf16x8*)(Vb + F2);
    bf16x8 vf3 = *(const bf16x8*)(Vb + F3);
    bf16x8 vf4 = *(const bf16x8*)(Vb + 4096 + F0);
    bf16x8 vf5 = *(const bf16x8*)(Vb + 4096 + F1);
    bf16x8 vf6 = *(const bf16x8*)(Vb + 4096 + F2);
    bf16x8 vf7 = *(const bf16x8*)(Vb + 4096 + F3);
    ot0 = __builtin_amdgcn_mfma_f32_32x32x16_bf16(vf0, pb00, ot0, 0, 0, 0);
    ot1 = __builtin_amdgcn_mfma_f32_32x32x16_bf16(vf4, pb00, ot1, 0, 0, 0);
    ot0 = __builtin_amdgcn_mfma_f32_32x32x16_bf16(vf1, pb01, ot0, 0, 0, 0);
    ot1 = __builtin_amdgcn_mfma_f32_32x32x16_bf16(vf5, pb01, ot1, 0, 0, 0);
    ot0 = __builtin_amdgcn_mfma_f32_32x32x16_bf16(vf2, pb10, ot0, 0, 0, 0);
    ot1 = __builtin_amdgcn_mfma_f32_32x32x16_bf16(vf6, pb10, ot1, 0, 0, 0);
    ot0 = __builtin_amdgcn_mfma_f32_32x32x16_bf16(vf3, pb11, ot0, 0, 0, 0);
    ot1 = __builtin_amdgcn_mfma_f32_32x32x16_bf16(vf7, pb11, ot1, 0, 0, 0);
  }
  lacc += __shfl_xor(lacc, 32);

  // ---- merge wave pairs (same qg, kh=0/1): plain add of (O, l); kh=0 writes ----
  __syncthreads();   // all PV reads done before mrg overwrites the LDS
  float* mrg = (float*)lds;                  // bytes [0,17.4K)
  const int slot = qg * 2176;
  if (kh) {
#pragma unroll
    for (int r = 0; r < 16; ++r) {
      mrg[slot + r * 64 + l] = ot0[r];
      mrg[slot + (16 + r) * 64 + l] = ot1[r];
    }
    mrg[slot + 2048 + l] = lacc;
  }
  __syncthreads();
  if (!kh) {
    float inv = 1.f / (lacc + mrg[slot + 2048 + l]);
    float* orow = att + (size_t)(b * SEQ + q0w + lrow) * DM + hcol + 4 * h;
#pragma unroll
    for (int G = 0; G < 4; ++G) {
      float4 w0;
      w0.x = (ot0[4 * G + 0] + mrg[slot + (4 * G + 0) * 64 + l]) * inv;
      w0.y = (ot0[4 * G + 1] + mrg[slot + (4 * G + 1) * 64 + l]) * inv;
      w0.z = (ot0[4 * G + 2] + mrg[slot + (4 * G + 2) * 64 + l]) * inv;
      w0.w = (ot0[4 * G + 3] + mrg[slot + (4 * G + 3) * 64 + l]) * inv;
      *(float4*)(orow + 8 * G) = w0;
      float4 w1;
      w1.x = (ot1[4 * G + 0] + mrg[slot + (16 + 4 * G + 0) * 64 + l]) * inv;
      w1.y = (ot1[4 * G + 1] + mrg[slot + (16 + 4 * G + 1) * 64 + l]) * inv;
      w1.z = (ot1[4 * G + 2] + mrg[slot + (16 + 4 * G + 2) * 64 + l]) * inv;
      w1.w = (ot1[4 * G + 3] + mrg[slot + (16 + 4 * G + 3) * 64 + l]) * inv;
      *(float4*)(orow + 32 + 8 * G) = w1;
    }
  }
}

// ---------------- residual + LayerNorm ----------------

__global__ __launch_bounds__(256) void k_ln(const float* __restrict__ att,
                                            const float* __restrict__ qin,
                                            const float* __restrict__ gamma,
                                            const float* __restrict__ beta,
                                            float* __restrict__ out) {
  __shared__ float rsum[4], rsum2[4];
  int row = blockIdx.x, t = threadIdx.x;
  size_t off = (size_t)row * DM + t * 4;
  float4 a = *(const float4*)(att + off);
  float4 q = *(const float4*)(qin + off);
  float4 x; x.x = a.x + q.x; x.y = a.y + q.y; x.z = a.z + q.z; x.w = a.w + q.w;
  float s = x.x + x.y + x.z + x.w;
  float s2 = x.x * x.x + x.y * x.y + x.z * x.z + x.w * x.w;
  for (int o2 = 1; o2 < 64; o2 <<= 1) { s += __shfl_xor(s, o2); s2 += __shfl_xor(s2, o2); }
  int w = t >> 6, l = t & 63;
  if (l == 0) { rsum[w] = s; rsum2[w] = s2; }
  __syncthreads();
  s = rsum[0] + rsum[1] + rsum[2] + rsum[3];
  s2 = rsum2[0] + rsum2[1] + rsum2[2] + rsum2[3];
  float mean = s * (1.f / DM);
  float var = s2 * (1.f / DM) - mean * mean;
  float rstd = rsqrtf(var + 1e-8f);
  float4 g = *(const float4*)(gamma + t * 4);
  float4 be = *(const float4*)(beta + t * 4);
  float4 r;
  r.x = (x.x - mean) * rstd * g.x + be.x;
  r.y = (x.y - mean) * rstd * g.y + be.y;
  r.z = (x.z - mean) * rstd * g.z + be.z;
  r.w = (x.w - mean) * rstd * g.w + be.w;
  *(float4*)(out + off) = r;
}

// ---------------- launch ----------------

extern "C" void kernel_launch(void* const* d_in, const int* in_sizes, int n_in,
                              void* d_out, int out_size, void* d_ws, size_t ws_size,
                              hipStream_t stream) {
  (void)in_sizes; (void)n_in; (void)out_size; (void)ws_size;
  const float* q     = (const float*)d_in[0];
  const float* k     = (const float*)d_in[1];
  const float* v     = (const float*)d_in[2];
  const float* Wq    = (const float*)d_in[3];
  const float* Wk    = (const float*)d_in[4];
  const float* Wv    = (const float*)d_in[5];
  const float* gamma = (const float*)d_in[6];
  const float* beta  = (const float*)d_in[7];
  float* out = (float*)d_out;
  char* ws = (char*)d_ws;

  const size_t ACT_B = 3ull * ROWS * DM * 2;   // 24 MB bf16 activations
  const size_t WT_B  = 3ull * DM * DM * 2;     //  6 MB bf16 transposed weights

  u16* actb  = (u16*)ws;                         //  0..24 MB (dead after GEMM)
  u16* wtb   = (u16*)(ws + ACT_B);               // 24..30 MB
  u16* projb = (u16*)(ws + ACT_B + WT_B);        // 30..54 MB (q/k/v projections)
  u16* vt    = (u16*)ws;                         //  0..8  MB (aliases dead actb)
  float* att = (float*)(ws + 8ull * 1024 * 1024);//  8..24 MB (aliases dead actb)

  k_cvt_act<<<dim3(2048, 1, 3), 256, 0, stream>>>(q, k, v, actb);
  k_cvt_wt<<<dim3(32, 32, 3), dim3(32, 8), 0, stream>>>(Wq, Wk, Wv, wtb);
  k_gemm<<<dim3(8, 32, 3), 256, 0, stream>>>(actb, wtb, projb);
  k_vt<<<dim3(SEQ / 64, NH * 2), 256, 0, stream>>>(projb + 2ull * ROWS * DM, vt);
  k_attn<<<1024, 256, 0, stream>>>(projb, projb + (size_t)ROWS * DM, vt, att);
  k_ln<<<ROWS, 256, 0, stream>>>(att, q, gamma, beta, out);
}